// Round 5
// baseline (419.764 us; speedup 1.0000x reference)
//
#include <hip/hip_runtime.h>
#include <hip/hip_bf16.h>
#include <hip/hip_cooperative_groups.h>

namespace cg = cooperative_groups;

// Problem constants: B=4, N=4096, DIM=1024; qkva = [B*N, 3*DIM]
#define SEQ_N 4096
#define BATCH 4
#define DIM 1024
#define M_ROWS (BATCH * SEQ_N)      // 16384
#define NCOLS (3 * DIM)             // 3072
#define KDIM DIM                    // 1024
#define CHUNK_L 16
#define NCHUNK (SEQ_N / CHUNK_L)    // 256
#define NCHANNEL (BATCH * DIM)      // 4096

using short8 = __attribute__((ext_vector_type(8))) short;
using f32x4  = __attribute__((ext_vector_type(4))) float;

static __device__ __forceinline__ unsigned short f2bf(float f) {
    union { float f; unsigned u; } v; v.f = f;
    unsigned r = v.u + 0x7fffu + ((v.u >> 16) & 1u);   // round-to-nearest-even
    return (unsigned short)(r >> 16);
}
static __device__ __forceinline__ float bf2f(unsigned short s) {
    union { unsigned u; float f; } v; v.u = ((unsigned)s) << 16;
    return v.f;
}

// ---------------- Fused RMSNorm (wave-per-row) + w fp32->bf16 conversion ------
__global__ __launch_bounds__(256) void prep_kernel(const float* __restrict__ x,
                                                   const float* __restrict__ gamma,
                                                   unsigned short* __restrict__ h,
                                                   const float* __restrict__ w,
                                                   unsigned short* __restrict__ wb) {
    if (blockIdx.x < 4096) {
        const int wave = threadIdx.x >> 6;
        const int lane = threadIdx.x & 63;
        const int row = blockIdx.x * 4 + wave;
        const float4* xr = reinterpret_cast<const float4*>(x + (size_t)row * DIM);
        const float4* gr = reinterpret_cast<const float4*>(gamma);
        float4 v[4];
        float ss = 0.f;
#pragma unroll
        for (int i = 0; i < 4; ++i) {
            v[i] = xr[i * 64 + lane];
            ss += v[i].x * v[i].x + v[i].y * v[i].y + v[i].z * v[i].z + v[i].w * v[i].w;
        }
#pragma unroll
        for (int off = 32; off >= 1; off >>= 1) ss += __shfl_xor(ss, off, 64);
        const float scale = 32.0f / fmaxf(sqrtf(ss), 1e-12f);   // sqrt(1024)=32
        ushort4* hr = reinterpret_cast<ushort4*>(h + (size_t)row * DIM);
#pragma unroll
        for (int i = 0; i < 4; ++i) {
            float4 g = gr[i * 64 + lane];
            ushort4 o;
            o.x = f2bf(v[i].x * scale * g.x);
            o.y = f2bf(v[i].y * scale * g.y);
            o.z = f2bf(v[i].z * scale * g.z);
            o.w = f2bf(v[i].w * scale * g.w);
            hr[i * 64 + lane] = o;
        }
    } else {
        const int i = (blockIdx.x - 4096) * 256 + threadIdx.x;   // < 786432
        float4 vv = reinterpret_cast<const float4*>(w)[i];
        ushort4 o;
        o.x = f2bf(vv.x); o.y = f2bf(vv.y); o.z = f2bf(vv.z); o.w = f2bf(vv.w);
        reinterpret_cast<ushort4*>(wb)[i] = o;
    }
}

// ---------------- GEMM: C[m,e] = sum_k A[m,k] * B[e,k], bf16 in, bf16 out ----
// m97-style: 128x128 tile, BK=32, 4 waves (2x2 of 64x64), 16x16x32 bf16 MFMA,
// global_load_lds width-16 staging. (Round-1 version; operand-swap variant
// regressed — do not revisit.)
__global__ __launch_bounds__(256) void gemm_bt_kernel(const unsigned short* __restrict__ A,
                                                      const unsigned short* __restrict__ B,
                                                      unsigned short* __restrict__ C) {
    __shared__ __align__(16) unsigned short sA[128 * 32];
    __shared__ __align__(16) unsigned short sB[128 * 32];

    const int tid  = threadIdx.x;
    const int lane = tid & 63;
    const int wave = tid >> 6;
    const int row0 = blockIdx.y * 128;
    const int col0 = blockIdx.x * 128;
    const int wm = (wave >> 1) * 64;
    const int wn = (wave & 1) * 64;
    const int fr = lane & 15;   // frag row/col within 16x16
    const int kq = lane >> 4;   // k-quad (which 8 of K=32)

    const unsigned short* agp = A + (size_t)(row0 + (tid >> 2)) * KDIM + (tid & 3) * 8;
    const unsigned short* bgp = B + (size_t)(col0 + (tid >> 2)) * KDIM + (tid & 3) * 8;

    f32x4 acc[4][4] = {};

    for (int k0 = 0; k0 < KDIM; k0 += 32) {
        __builtin_amdgcn_global_load_lds(
            (const __attribute__((address_space(1))) void*)(agp),
            (__attribute__((address_space(3))) void*)(&sA[tid * 8]), 16, 0, 0);
        __builtin_amdgcn_global_load_lds(
            (const __attribute__((address_space(1))) void*)(agp + 64 * KDIM),
            (__attribute__((address_space(3))) void*)(&sA[2048 + tid * 8]), 16, 0, 0);
        __builtin_amdgcn_global_load_lds(
            (const __attribute__((address_space(1))) void*)(bgp),
            (__attribute__((address_space(3))) void*)(&sB[tid * 8]), 16, 0, 0);
        __builtin_amdgcn_global_load_lds(
            (const __attribute__((address_space(1))) void*)(bgp + 64 * KDIM),
            (__attribute__((address_space(3))) void*)(&sB[2048 + tid * 8]), 16, 0, 0);
        agp += 32; bgp += 32;
        __syncthreads();

        short8 af[4], bf[4];
#pragma unroll
        for (int i = 0; i < 4; ++i)
            af[i] = *reinterpret_cast<const short8*>(&sA[(wm + i * 16 + fr) * 32 + kq * 8]);
#pragma unroll
        for (int j = 0; j < 4; ++j)
            bf[j] = *reinterpret_cast<const short8*>(&sB[(wn + j * 16 + fr) * 32 + kq * 8]);
#pragma unroll
        for (int i = 0; i < 4; ++i)
#pragma unroll
            for (int j = 0; j < 4; ++j)
                acc[i][j] = __builtin_amdgcn_mfma_f32_16x16x32_bf16(af[i], bf[j], acc[i][j], 0, 0, 0);
        __syncthreads();
    }

    // epilogue: C/D layout col=lane&15, row=(lane>>4)*4+reg
#pragma unroll
    for (int i = 0; i < 4; ++i) {
#pragma unroll
        for (int j = 0; j < 4; ++j) {
#pragma unroll
            for (int r = 0; r < 4; ++r) {
                int row = row0 + wm + i * 16 + kq * 4 + r;
                int col = col0 + wn + j * 16 + fr;
                C[(size_t)row * NCOLS + col] = f2bf(acc[i][j][r]);
            }
        }
    }
}

// ---------------- Fused scan (cooperative, one dispatch) ----------------
// Grid: 512 blocks x 256 threads (2 blocks/CU -> co-residency guaranteed).
// Phase 1: each block computes per-chunk aggregates for 2 (chunk,batch) pairs.
// Phase 2: blocks 0..15 do the 256-link serial scan over chunk aggregates.
// Phase 3: each block rescans its 2 pairs with the correct entry state.
__global__ __launch_bounds__(256) void fused_scan_kernel(const unsigned short* __restrict__ qkva,
                                                         float2* __restrict__ AY,
                                                         float* __restrict__ Sin,
                                                         float* __restrict__ out) {
    cg::grid_group grid = cg::this_grid();
    const int tid = threadIdx.x;     // quad index 0..255; d = 4*tid

    // ---- Phase 1: per-chunk aggregates (A = prod a, Y = local scan value) ----
#pragma unroll
    for (int pp = 0; pp < 2; ++pp) {
        const int p = blockIdx.x + pp * 512;     // pair id 0..1023
        const int c = p & 255, b = p >> 8;
        const unsigned short* base = qkva + ((size_t)b * SEQ_N + c * CHUNK_L) * NCOLS;
        float s[4] = {0.f, 0.f, 0.f, 0.f};
        float A[4] = {1.f, 1.f, 1.f, 1.f};
#pragma unroll 4
        for (int n = 0; n < CHUNK_L; ++n) {
            ushort4 kv4 = reinterpret_cast<const ushort4*>(base + (size_t)n * NCOLS + DIM)[tid];
            ushort4 av4 = reinterpret_cast<const ushort4*>(base + (size_t)n * NCOLS + 2 * DIM)[tid];
            float kv[4] = {bf2f(kv4.x), bf2f(kv4.y), bf2f(kv4.z), bf2f(kv4.w)};
            float av[4] = {bf2f(av4.x), bf2f(av4.y), bf2f(av4.z), bf2f(av4.w)};
#pragma unroll
            for (int t = 0; t < 4; ++t) {
                float a = 1.f / (1.f + __expf(-av[t]));
                s[t] = a * s[t] + kv[t];
                A[t] *= a;
            }
        }
        float4* o = reinterpret_cast<float4*>(AY + (size_t)c * NCHANNEL + b * DIM);
        float4 p0, p1;
        p0.x = A[0]; p0.y = s[0]; p0.z = A[1]; p0.w = s[1];
        p1.x = A[2]; p1.y = s[2]; p1.z = A[3]; p1.w = s[3];
        o[2 * tid]     = p0;
        o[2 * tid + 1] = p1;
    }

    grid.sync();

    // ---- Phase 2: serial exclusive scan over the 256 chunk aggregates ----
    if (blockIdx.x < 16) {
        const int ch = blockIdx.x * 256 + tid;   // 0..4095
        float s = 0.f;
#pragma unroll 8
        for (int c = 0; c < NCHUNK; ++c) {
            Sin[(size_t)c * NCHANNEL + ch] = s;
            float2 ay = AY[(size_t)c * NCHANNEL + ch];
            s = ay.x * s + ay.y;
        }
    }

    grid.sync();

    // ---- Phase 3: rescan chunks with correct entry state, out = q * y ----
#pragma unroll
    for (int pp = 0; pp < 2; ++pp) {
        const int p = blockIdx.x + pp * 512;
        const int c = p & 255, b = p >> 8;
        const unsigned short* base = qkva + ((size_t)b * SEQ_N + c * CHUNK_L) * NCOLS;
        float* obase = out + ((size_t)b * SEQ_N + c * CHUNK_L) * DIM;
        float4 s4 = reinterpret_cast<const float4*>(Sin + (size_t)c * NCHANNEL + b * DIM)[tid];
        float s[4] = {s4.x, s4.y, s4.z, s4.w};
#pragma unroll 4
        for (int n = 0; n < CHUNK_L; ++n) {
            ushort4 kv4 = reinterpret_cast<const ushort4*>(base + (size_t)n * NCOLS + DIM)[tid];
            ushort4 av4 = reinterpret_cast<const ushort4*>(base + (size_t)n * NCOLS + 2 * DIM)[tid];
            ushort4 q4  = reinterpret_cast<const ushort4*>(base + (size_t)n * NCOLS)[tid];
            float kv[4] = {bf2f(kv4.x), bf2f(kv4.y), bf2f(kv4.z), bf2f(kv4.w)};
            float av[4] = {bf2f(av4.x), bf2f(av4.y), bf2f(av4.z), bf2f(av4.w)};
            float q[4]  = {bf2f(q4.x),  bf2f(q4.y),  bf2f(q4.z),  bf2f(q4.w)};
            float4 o;
            {
                float a0 = 1.f / (1.f + __expf(-av[0])); s[0] = a0 * s[0] + kv[0]; o.x = q[0] * s[0];
                float a1 = 1.f / (1.f + __expf(-av[1])); s[1] = a1 * s[1] + kv[1]; o.y = q[1] * s[1];
                float a2 = 1.f / (1.f + __expf(-av[2])); s[2] = a2 * s[2] + kv[2]; o.z = q[2] * s[2];
                float a3 = 1.f / (1.f + __expf(-av[3])); s[3] = a3 * s[3] + kv[3]; o.w = q[3] * s[3];
            }
            reinterpret_cast<float4*>(obase + (size_t)n * DIM)[tid] = o;
        }
    }
}

extern "C" void kernel_launch(void* const* d_in, const int* in_sizes, int n_in,
                              void* d_out, int out_size, void* d_ws, size_t ws_size,
                              hipStream_t stream) {
    const float* x     = (const float*)d_in[0];   // [4,4096,1024]
    const float* w     = (const float*)d_in[1];   // [3072,1024]
    const float* gamma = (const float*)d_in[2];   // [1024]
    float* out = (float*)d_out;                   // [4,4096,1024]

    char* ws = (char*)d_ws;
    // workspace layout (bytes):
    unsigned short* wb   = (unsigned short*)(ws);             // 3072*1024*2   = 6,291,456
    unsigned short* h    = (unsigned short*)(ws + 6291456);   // 16384*1024*2  = 33,554,432
    unsigned short* qkva = (unsigned short*)(ws + 39845888);  // 16384*3072*2  = 100,663,296
    // Scan temporaries live inside h's region — h is dead after the GEMM.
    float2* AY  = (float2*)(ws + 6291456);                    // 256*4096*8 = 8,388,608
    float*  Sin = (float*)(ws + 6291456 + 8388608);           // 256*4096*4 = 4,194,304
    // total ws: 140,509,184 bytes

    prep_kernel<<<4096 + 3072, 256, 0, stream>>>(x, gamma, h, w, wb);
    gemm_bt_kernel<<<dim3(NCOLS / 128, M_ROWS / 128), 256, 0, stream>>>(h, wb, qkva);

    void* args[] = {(void*)&qkva, (void*)&AY, (void*)&Sin, (void*)&out};
    hipLaunchCooperativeKernel((void*)fused_scan_kernel, dim3(512), dim3(256),
                               args, 0, stream);
}

// Round 6
// 325.549 us; speedup vs baseline: 1.2894x; 1.2894x over previous
//
#include <hip/hip_runtime.h>
#include <hip/hip_bf16.h>

// Problem constants: B=4, N=4096, DIM=1024; qkva = [B*N, 3*DIM]
#define SEQ_N 4096
#define BATCH 4
#define DIM 1024
#define M_ROWS (BATCH * SEQ_N)      // 16384
#define NCOLS (3 * DIM)             // 3072
#define KDIM DIM                    // 1024
#define CHUNK_L 16
#define NCHUNK (SEQ_N / CHUNK_L)    // 256
#define NCHANNEL (BATCH * DIM)      // 4096

using short8  = __attribute__((ext_vector_type(8))) short;
using f32x16  = __attribute__((ext_vector_type(16))) float;

static __device__ __forceinline__ unsigned short f2bf(float f) {
    union { float f; unsigned u; } v; v.f = f;
    unsigned r = v.u + 0x7fffu + ((v.u >> 16) & 1u);   // round-to-nearest-even
    return (unsigned short)(r >> 16);
}
static __device__ __forceinline__ float bf2f(unsigned short s) {
    union { unsigned u; float f; } v; v.u = ((unsigned)s) << 16;
    return v.f;
}

// ---------------- Fused RMSNorm (wave-per-row) + w fp32->bf16 conversion ------
__global__ __launch_bounds__(256) void prep_kernel(const float* __restrict__ x,
                                                   const float* __restrict__ gamma,
                                                   unsigned short* __restrict__ h,
                                                   const float* __restrict__ w,
                                                   unsigned short* __restrict__ wb) {
    if (blockIdx.x < 4096) {
        const int wave = threadIdx.x >> 6;
        const int lane = threadIdx.x & 63;
        const int row = blockIdx.x * 4 + wave;
        const float4* xr = reinterpret_cast<const float4*>(x + (size_t)row * DIM);
        const float4* gr = reinterpret_cast<const float4*>(gamma);
        float4 v[4];
        float ss = 0.f;
#pragma unroll
        for (int i = 0; i < 4; ++i) {
            v[i] = xr[i * 64 + lane];
            ss += v[i].x * v[i].x + v[i].y * v[i].y + v[i].z * v[i].z + v[i].w * v[i].w;
        }
#pragma unroll
        for (int off = 32; off >= 1; off >>= 1) ss += __shfl_xor(ss, off, 64);
        const float scale = 32.0f / fmaxf(sqrtf(ss), 1e-12f);   // sqrt(1024)=32
        ushort4* hr = reinterpret_cast<ushort4*>(h + (size_t)row * DIM);
#pragma unroll
        for (int i = 0; i < 4; ++i) {
            float4 g = gr[i * 64 + lane];
            ushort4 o;
            o.x = f2bf(v[i].x * scale * g.x);
            o.y = f2bf(v[i].y * scale * g.y);
            o.z = f2bf(v[i].z * scale * g.z);
            o.w = f2bf(v[i].w * scale * g.w);
            hr[i * 64 + lane] = o;
        }
    } else {
        const int i = (blockIdx.x - 4096) * 256 + threadIdx.x;   // < 786432
        float4 vv = reinterpret_cast<const float4*>(w)[i];
        ushort4 o;
        o.x = f2bf(vv.x); o.y = f2bf(vv.y); o.z = f2bf(vv.z); o.w = f2bf(vv.w);
        reinterpret_cast<ushort4*>(wb)[i] = o;
    }
}

// ---------------- GEMM: C[m,e] = sum_k A[m,k] * B[e,k], bf16 in, bf16 out ----
// m97-style staging (128x128 tile, BK=32, 4 waves of 64x64, global_load_lds
// width-16), inner compute switched to 32x32x16 bf16 MFMA: 8 MFMA x 8.07cy
// = 64.6cy per K=32 per wave vs 16 x 4.85 = 77.6cy for 16x16x32.
// Layouts (m74/m101-verified): A/B frag [m=lane&31][k=(lane>>5)*8+j];
// C/D col=lane&31, row=(reg&3)+8*(reg>>2)+4*(lane>>5).
__global__ __launch_bounds__(256) void gemm_bt_kernel(const unsigned short* __restrict__ A,
                                                      const unsigned short* __restrict__ B,
                                                      unsigned short* __restrict__ C) {
    __shared__ __align__(16) unsigned short sA[128 * 32];
    __shared__ __align__(16) unsigned short sB[128 * 32];

    const int tid  = threadIdx.x;
    const int lane = tid & 63;
    const int wave = tid >> 6;
    const int row0 = blockIdx.y * 128;
    const int col0 = blockIdx.x * 128;
    const int wm = (wave >> 1) * 64;
    const int wn = (wave & 1) * 64;
    const int m32 = lane & 31;   // row (A) / col (B) within a 32-tile
    const int kh  = lane >> 5;   // k-half: k offset 8*kh within a K=16 step

    const unsigned short* agp = A + (size_t)(row0 + (tid >> 2)) * KDIM + (tid & 3) * 8;
    const unsigned short* bgp = B + (size_t)(col0 + (tid >> 2)) * KDIM + (tid & 3) * 8;

    f32x16 acc[2][2] = {};

    for (int k0 = 0; k0 < KDIM; k0 += 32) {
        __builtin_amdgcn_global_load_lds(
            (const __attribute__((address_space(1))) void*)(agp),
            (__attribute__((address_space(3))) void*)(&sA[tid * 8]), 16, 0, 0);
        __builtin_amdgcn_global_load_lds(
            (const __attribute__((address_space(1))) void*)(agp + 64 * KDIM),
            (__attribute__((address_space(3))) void*)(&sA[2048 + tid * 8]), 16, 0, 0);
        __builtin_amdgcn_global_load_lds(
            (const __attribute__((address_space(1))) void*)(bgp),
            (__attribute__((address_space(3))) void*)(&sB[tid * 8]), 16, 0, 0);
        __builtin_amdgcn_global_load_lds(
            (const __attribute__((address_space(1))) void*)(bgp + 64 * KDIM),
            (__attribute__((address_space(3))) void*)(&sB[2048 + tid * 8]), 16, 0, 0);
        agp += 32; bgp += 32;
        __syncthreads();

        short8 af[2][2], bf[2][2];   // [ks][tile]
#pragma unroll
        for (int ks = 0; ks < 2; ++ks) {
#pragma unroll
            for (int mi = 0; mi < 2; ++mi) {
                af[ks][mi] = *reinterpret_cast<const short8*>(
                    &sA[(wm + mi * 32 + m32) * 32 + ks * 16 + kh * 8]);
                bf[ks][mi] = *reinterpret_cast<const short8*>(
                    &sB[(wn + mi * 32 + m32) * 32 + ks * 16 + kh * 8]);
            }
        }
#pragma unroll
        for (int ks = 0; ks < 2; ++ks)
#pragma unroll
            for (int mi = 0; mi < 2; ++mi)
#pragma unroll
                for (int nj = 0; nj < 2; ++nj)
                    acc[mi][nj] = __builtin_amdgcn_mfma_f32_32x32x16_bf16(
                        af[ks][mi], bf[ks][nj], acc[mi][nj], 0, 0, 0);
        __syncthreads();
    }

    // epilogue: col=lane&31, row=(r&3)+8*(r>>2)+4*kh
#pragma unroll
    for (int mi = 0; mi < 2; ++mi) {
#pragma unroll
        for (int nj = 0; nj < 2; ++nj) {
            const int col = col0 + wn + nj * 32 + m32;
#pragma unroll
            for (int r = 0; r < 16; ++r) {
                const int row = row0 + wm + mi * 32 + (r & 3) + 8 * (r >> 2) + 4 * kh;
                C[(size_t)row * NCOLS + col] = f2bf(acc[mi][nj][r]);
            }
        }
    }
}

// ---------------- Scan phase 1: per-chunk aggregates, interleaved (A,Y) float2
// grid (256 chunks, 4 batches) x 256 threads, 4 channels/thread via ushort4.
__global__ __launch_bounds__(256) void chunk_agg_kernel(const unsigned short* __restrict__ qkva,
                                                        float2* __restrict__ AY) {
    const int c = blockIdx.x, b = blockIdx.y;
    const int d4 = threadIdx.x;                        // quad index 0..255; d = 4*d4
    const unsigned short* base = qkva + ((size_t)b * SEQ_N + c * CHUNK_L) * NCOLS;
    float s[4] = {0.f, 0.f, 0.f, 0.f};
    float A[4] = {1.f, 1.f, 1.f, 1.f};
#pragma unroll 4
    for (int n = 0; n < CHUNK_L; ++n) {
        ushort4 kv4 = reinterpret_cast<const ushort4*>(base + (size_t)n * NCOLS + DIM)[d4];
        ushort4 av4 = reinterpret_cast<const ushort4*>(base + (size_t)n * NCOLS + 2 * DIM)[d4];
        float kv[4] = {bf2f(kv4.x), bf2f(kv4.y), bf2f(kv4.z), bf2f(kv4.w)};
        float av[4] = {bf2f(av4.x), bf2f(av4.y), bf2f(av4.z), bf2f(av4.w)};
#pragma unroll
        for (int t = 0; t < 4; ++t) {
            float a = 1.f / (1.f + __expf(-av[t]));
            s[t] = a * s[t] + kv[t];
            A[t] *= a;
        }
    }
    float4* o = reinterpret_cast<float4*>(AY + (size_t)c * NCHANNEL + b * DIM);
    float4 p0, p1;
    p0.x = A[0]; p0.y = s[0]; p0.z = A[1]; p0.w = s[1];
    p1.x = A[2]; p1.y = s[2]; p1.z = A[3]; p1.w = s[3];
    o[2 * d4]     = p0;
    o[2 * d4 + 1] = p1;
}

// ---------------- Scan phase 2: sequential scan over chunk aggregates
// 64 blocks x 64 threads (64 CUs engaged), one float2 load per link.
__global__ __launch_bounds__(64) void agg_scan_kernel(const float2* __restrict__ AY,
                                                      float* __restrict__ Sin) {
    const int ch = blockIdx.x * 64 + threadIdx.x;   // 0..4095
    float s = 0.f;
#pragma unroll 8
    for (int c = 0; c < NCHUNK; ++c) {
        Sin[(size_t)c * NCHANNEL + ch] = s;
        float2 ay = AY[(size_t)c * NCHANNEL + ch];
        s = ay.x * s + ay.y;
    }
}

// ---------------- Scan phase 3: rescan chunk with correct entry state, out = q*y
__global__ __launch_bounds__(256) void apply_kernel(const unsigned short* __restrict__ qkva,
                                                    const float* __restrict__ Sin,
                                                    float* __restrict__ out) {
    const int c = blockIdx.x, b = blockIdx.y;
    const int d4 = threadIdx.x;                        // quad index 0..255; d = 4*d4
    const unsigned short* base = qkva + ((size_t)b * SEQ_N + c * CHUNK_L) * NCOLS;
    float* obase = out + ((size_t)b * SEQ_N + c * CHUNK_L) * DIM;
    float4 s4 = reinterpret_cast<const float4*>(Sin + (size_t)c * NCHANNEL + b * DIM)[d4];
    float s[4] = {s4.x, s4.y, s4.z, s4.w};
#pragma unroll 4
    for (int n = 0; n < CHUNK_L; ++n) {
        ushort4 kv4 = reinterpret_cast<const ushort4*>(base + (size_t)n * NCOLS + DIM)[d4];
        ushort4 av4 = reinterpret_cast<const ushort4*>(base + (size_t)n * NCOLS + 2 * DIM)[d4];
        ushort4 q4  = reinterpret_cast<const ushort4*>(base + (size_t)n * NCOLS)[d4];
        float kv[4] = {bf2f(kv4.x), bf2f(kv4.y), bf2f(kv4.z), bf2f(kv4.w)};
        float av[4] = {bf2f(av4.x), bf2f(av4.y), bf2f(av4.z), bf2f(av4.w)};
        float q[4]  = {bf2f(q4.x),  bf2f(q4.y),  bf2f(q4.z),  bf2f(q4.w)};
        float4 o;
        {
            float a0 = 1.f / (1.f + __expf(-av[0])); s[0] = a0 * s[0] + kv[0]; o.x = q[0] * s[0];
            float a1 = 1.f / (1.f + __expf(-av[1])); s[1] = a1 * s[1] + kv[1]; o.y = q[1] * s[1];
            float a2 = 1.f / (1.f + __expf(-av[2])); s[2] = a2 * s[2] + kv[2]; o.z = q[2] * s[2];
            float a3 = 1.f / (1.f + __expf(-av[3])); s[3] = a3 * s[3] + kv[3]; o.w = q[3] * s[3];
        }
        reinterpret_cast<float4*>(obase + (size_t)n * DIM)[d4] = o;
    }
}

extern "C" void kernel_launch(void* const* d_in, const int* in_sizes, int n_in,
                              void* d_out, int out_size, void* d_ws, size_t ws_size,
                              hipStream_t stream) {
    const float* x     = (const float*)d_in[0];   // [4,4096,1024]
    const float* w     = (const float*)d_in[1];   // [3072,1024]
    const float* gamma = (const float*)d_in[2];   // [1024]
    float* out = (float*)d_out;                   // [4,4096,1024]

    char* ws = (char*)d_ws;
    // workspace layout (bytes):
    unsigned short* wb   = (unsigned short*)(ws);             // 3072*1024*2   = 6,291,456
    unsigned short* h    = (unsigned short*)(ws + 6291456);   // 16384*1024*2  = 33,554,432
    unsigned short* qkva = (unsigned short*)(ws + 39845888);  // 16384*3072*2  = 100,663,296
    // Scan temporaries live inside h's region — h is dead after the GEMM.
    float2* AY  = (float2*)(ws + 6291456);                    // 256*4096*8 = 8,388,608
    float*  Sin = (float*)(ws + 6291456 + 8388608);           // 256*4096*4 = 4,194,304
    // total ws: 140,509,184 bytes

    prep_kernel<<<4096 + 3072, 256, 0, stream>>>(x, gamma, h, w, wb);
    gemm_bt_kernel<<<dim3(NCOLS / 128, M_ROWS / 128), 256, 0, stream>>>(h, wb, qkva);
    chunk_agg_kernel<<<dim3(NCHUNK, BATCH), 256, 0, stream>>>(qkva, AY);
    agg_scan_kernel<<<NCHANNEL / 64, 64, 0, stream>>>(AY, Sin);
    apply_kernel<<<dim3(NCHUNK, BATCH), 256, 0, stream>>>(qkva, Sin, out);
}